// Round 6
// baseline (23.255 us; speedup 1.0000x reference)
//
#include <hip/hip_runtime.h>

// Problem constants (from reference): B=8, S=2048, D=1024, fp32 in/out.
#define BB 8
#define SS 2048
#define DD 1024
#define SC 8                    // S-chunks per (b, col-tile)
#define NI4 (BB * DD / 4)       // 2048 float4s in xs

using f4 = __attribute__((ext_vector_type(4))) float;

// Identity: softmax rows sum to 1 -> attention == 1, so
//   out[b,e] = (sum_s x[b,s,:]) . Wv[e,:] + S * bv[e]
// Ledger: stage-1 (the 64 MiB x read) has been ~17us across 3 configs
// (4/16 waves-CU, row-major/col-slab) => ~3.9 TB/s wall. This round tests
// the last two levers: max occupancy (32 waves/CU) + non-temporal loads.

// ---------------------------------------------------------------------------
// Stage 1: part[sc][b*D + dt*32 .. +31] = sum of chunk sc's 256 rows.
// grid = 8b x 32dt x 8sc = 2048 blocks (8/CU -> 32 waves/CU, HW max).
// Thread (rg=t>>3, f4i=t&7): sums 8 rows (stride 32) of its float4 column.
// Non-temporal loads: x is read-once per replay; minimize L2 pressure.
// ---------------------------------------------------------------------------
__global__ __launch_bounds__(256) void colsum_part(
    const float* __restrict__ x, float* __restrict__ part) {
    const int bid = blockIdx.x;
    const int b    = bid >> 8;
    const int rest = bid & 255;
    const int dt   = rest >> 3;      // 32-col tile
    const int sc   = rest & 7;       // S-chunk
    const int t    = threadIdx.x;
    const int f4i  = t & 7;
    const int rg   = t >> 3;         // 0..31
    const int lane = t & 63;
    const int w    = t >> 6;         // wave 0..3

    const f4* xp = (const f4*)(x + (size_t)b * SS * DD
                                 + (size_t)sc * (SS / SC) * DD + dt * 32);
    f4 a = (f4)(0.f);
#pragma unroll
    for (int it = 0; it < (SS / SC) / 32; ++it) {   // 8 iterations
        const int r = it * 32 + rg;
        f4 v = __builtin_nontemporal_load(&xp[(size_t)r * (DD / 4) + f4i]);
        a += v;
    }
    // reduce over rowgroups within wave (lane bits 3..5)
#pragma unroll
    for (int off = 8; off <= 32; off <<= 1) {
        a.x += __shfl_xor(a.x, off);
        a.y += __shfl_xor(a.y, off);
        a.z += __shfl_xor(a.z, off);
        a.w += __shfl_xor(a.w, off);
    }
    __shared__ f4 lds[4][8];
    if (lane < 8) lds[w][lane] = a;
    __syncthreads();
    if (t < 8) {
        f4 r4 = lds[0][t] + lds[1][t] + lds[2][t] + lds[3][t];
        ((f4*)part)[(size_t)sc * NI4 + b * 256 + dt * 8 + t] = r4;
    }
}

// ---------------------------------------------------------------------------
// Stage 2: xs[i4] = sum_sc part[sc][i4].  8 blocks x 256 threads, float4.
// 64 KiB read (L2-hot), fully coalesced.
// ---------------------------------------------------------------------------
__global__ __launch_bounds__(256) void colsum_reduce(
    const float* __restrict__ part, float* __restrict__ xs) {
    const int i4 = blockIdx.x * 256 + threadIdx.x;   // 0..2047
    const f4* p = (const f4*)part;
    f4 a = (f4)(0.f);
#pragma unroll
    for (int sc = 0; sc < SC; ++sc) a += p[(size_t)sc * NI4 + i4];
    ((f4*)xs)[i4] = a;
}

// ---------------------------------------------------------------------------
// Stage 3: out[b,e] = xs[b,:] . Wv[e,:] + S * bv[e]. One block per e.
// ---------------------------------------------------------------------------
__global__ __launch_bounds__(256) void gemv_out(
    const float* __restrict__ Wv, const float* __restrict__ bv,
    const float* __restrict__ xs, float* __restrict__ out) {
    const int e = blockIdx.x;
    const int t = threadIdx.x;
    const int lane = t & 63;
    const int wid = t >> 6;  // 4 waves

    const f4 w = ((const f4*)(Wv + (size_t)e * DD))[t];

    float acc[BB];
#pragma unroll
    for (int b = 0; b < BB; ++b) {
        f4 xv = ((const f4*)(xs + b * DD))[t];
        acc[b] = w.x * xv.x + w.y * xv.y + w.z * xv.z + w.w * xv.w;
    }

    __shared__ float lds[BB * 4];
#pragma unroll
    for (int b = 0; b < BB; ++b) {
        float v = acc[b];
#pragma unroll
        for (int off = 32; off > 0; off >>= 1) v += __shfl_down(v, off);
        if (lane == 0) lds[b * 4 + wid] = v;
    }
    __syncthreads();
    if (t < BB) {
        out[(size_t)t * DD + e] = lds[t * 4 + 0] + lds[t * 4 + 1]
                                + lds[t * 4 + 2] + lds[t * 4 + 3]
                                + (float)SS * bv[e];
    }
}

// Inputs: 0=x [B,S,D], 1=Wq, 2=bq, 3=Wk, 4=bk, 5=Wv, 6=bv. Output: [B,D] fp32.
extern "C" void kernel_launch(void* const* d_in, const int* in_sizes, int n_in,
                              void* d_out, int out_size, void* d_ws, size_t ws_size,
                              hipStream_t stream) {
    const float* x  = (const float*)d_in[0];
    const float* Wv = (const float*)d_in[5];
    const float* bv = (const float*)d_in[6];
    float* out = (float*)d_out;

    float* part = (float*)d_ws;              // SC * 8192 floats = 256 KiB
    float* xs   = part + (size_t)SC * BB * DD; // 32 KiB

    colsum_part<<<2048, 256, 0, stream>>>(x, part);
    colsum_reduce<<<SC, 256, 0, stream>>>(part, xs);
    gemv_out<<<DD, 256, 0, stream>>>(Wv, bv, xs, out);
}